// Round 5
// baseline (174.625 us; speedup 1.0000x reference)
//
#include <hip/hip_runtime.h>
#include <hip/hip_bf16.h>

// out[b, t] = w[t] * q0[b] + b[t]   (B x T x 1 output, fp32)
// Row-band layout (T==4096 fast path): each 256-thread block owns a
// contiguous 256 KiB band (16 full rows). Each thread holds 4 w/b float4
// pairs in registers (t4 = tid + 256k), so every 16 KiB row is one fully
// contiguous wave-coalesced burst. 2048 blocks = 8/CU = full occupancy.

__device__ inline float4 fma4(float q, const float4& w, const float4& b) {
    float4 o;
    o.x = fmaf(q, w.x, b.x);
    o.y = fmaf(q, w.y, b.y);
    o.z = fmaf(q, w.z, b.z);
    o.w = fmaf(q, w.w, b.w);
    return o;
}

// Specialized: T4 == 1024 (T == 4096).
__global__ __launch_bounds__(256)
void pn_rowband(const float* __restrict__ q0,
                const float4* __restrict__ w4,
                const float4* __restrict__ b4,
                float4* __restrict__ out4,
                int rows_per_blk) {
    const int T4 = 1024;
    const int tid = threadIdx.x;
    float4 wv0 = w4[tid];
    float4 wv1 = w4[tid + 256];
    float4 wv2 = w4[tid + 512];
    float4 wv3 = w4[tid + 768];
    float4 bv0 = b4[tid];
    float4 bv1 = b4[tid + 256];
    float4 bv2 = b4[tid + 512];
    float4 bv3 = b4[tid + 768];

    const int r0 = blockIdx.x * rows_per_blk;
    #pragma unroll 1
    for (int r = 0; r < rows_per_blk; r += 2) {
        const float2 q2 = *reinterpret_cast<const float2*>(q0 + r0 + r);
        float4* p0 = out4 + (long long)(r0 + r) * T4 + tid;
        p0[0]   = fma4(q2.x, wv0, bv0);
        p0[256] = fma4(q2.x, wv1, bv1);
        p0[512] = fma4(q2.x, wv2, bv2);
        p0[768] = fma4(q2.x, wv3, bv3);
        float4* p1 = p0 + T4;
        p1[0]   = fma4(q2.y, wv0, bv0);
        p1[256] = fma4(q2.y, wv1, bv1);
        p1[512] = fma4(q2.y, wv2, bv2);
        p1[768] = fma4(q2.y, wv3, bv3);
    }
}

// General column-stationary fallback (round-4 kernel).
__global__ __launch_bounds__(256)
void pn_colkernel(const float* __restrict__ q0,
                  const float4* __restrict__ w4,
                  const float4* __restrict__ b4,
                  float4* __restrict__ out4,
                  int T4, int rows_per_blk) {
    const int t4 = blockIdx.y * blockDim.x + threadIdx.x;
    const float4 wv = w4[t4];
    const float4 bv = b4[t4];
    const int r0 = blockIdx.x * rows_per_blk;

    #pragma unroll 1
    for (int r = 0; r < rows_per_blk; r += 4) {
        const float4 qv = *reinterpret_cast<const float4*>(q0 + r0 + r);
        const long long base = (long long)(r0 + r) * T4 + t4;
        out4[base]           = fma4(qv.x, wv, bv);
        out4[base + T4]      = fma4(qv.y, wv, bv);
        out4[base + 2 * T4]  = fma4(qv.z, wv, bv);
        out4[base + 3 * T4]  = fma4(qv.w, wv, bv);
    }
}

// Scalar fallback for odd shapes.
__global__ __launch_bounds__(256)
void pn_rowkernel_scalar(const float* __restrict__ q0,
                         const float* __restrict__ w,
                         const float* __restrict__ b,
                         float* __restrict__ out,
                         int T) {
    const int row = blockIdx.x;
    const float q = q0[row];
    float* __restrict__ orow = out + (long long)row * T;
    for (int j = threadIdx.x; j < T; j += blockDim.x) {
        orow[j] = fmaf(q, w[j], b[j]);
    }
}

extern "C" void kernel_launch(void* const* d_in, const int* in_sizes, int n_in,
                              void* d_out, int out_size, void* d_ws, size_t ws_size,
                              hipStream_t stream) {
    const float* q0 = (const float*)d_in[0];   // [B, 1]
    const float* w  = (const float*)d_in[1];   // [T]
    const float* b  = (const float*)d_in[2];   // [T]
    float* out = (float*)d_out;                // [B, T, 1]

    const int B = in_sizes[0];
    const int T = in_sizes[1];

    if (T == 4096 && (B % 16) == 0) {
        const int rows_per_blk = 16;           // 2048 blocks = 8/CU, 32 waves/CU
        pn_rowband<<<B / rows_per_blk, 256, 0, stream>>>(
            q0,
            reinterpret_cast<const float4*>(w),
            reinterpret_cast<const float4*>(b),
            reinterpret_cast<float4*>(out),
            rows_per_blk);
        return;
    }

    if ((T & 3) == 0) {
        const int T4 = T >> 2;
        const int rows_per_blk = 64;
        if ((T4 % 256) == 0 && (B % rows_per_blk) == 0) {
            dim3 grid(B / rows_per_blk, T4 / 256);
            pn_colkernel<<<grid, 256, 0, stream>>>(
                q0,
                reinterpret_cast<const float4*>(w),
                reinterpret_cast<const float4*>(b),
                reinterpret_cast<float4*>(out),
                T4, rows_per_blk);
            return;
        }
    }
    pn_rowkernel_scalar<<<B, 256, 0, stream>>>(q0, w, b, out, T);
}

// Round 6
// 107.311 us; speedup vs baseline: 1.6273x; 1.6273x over previous
//
#include <hip/hip_runtime.h>
#include <hip/hip_bf16.h>

// out[b, t] = w[t] * q0[b] + b[t]   (B x T x 1 output, fp32)
// fillBuffer-shaped grid-stride kernel (T==4096 fast path): thread j writes
// linear float4 index j, j+stride, ... — identical address stream to the
// runtime's memset, which sustains 6.5-6.8 TB/s on this chip. Grid*block is a
// multiple of T4=1024 so each thread's column (i & 1023) is loop-invariant ->
// w/b held in registers, zero refetch.

__device__ inline float4 fma4(float q, const float4& w, const float4& b) {
    float4 o;
    o.x = fmaf(q, w.x, b.x);
    o.y = fmaf(q, w.y, b.y);
    o.z = fmaf(q, w.z, b.z);
    o.w = fmaf(q, w.w, b.w);
    return o;
}

// Requires: gridDim.x * blockDim.x % 1024 == 0, T4 == 1024.
__global__ __launch_bounds__(256)
void pn_gridstride(const float* __restrict__ q0,
                   const float4* __restrict__ w4,
                   const float4* __restrict__ b4,
                   float4* __restrict__ out4,
                   long long n4) {
    const long long stride = (long long)gridDim.x * blockDim.x;   // 524288
    long long i = (long long)blockIdx.x * blockDim.x + threadIdx.x;
    const int t4 = (int)(i & 1023);
    const float4 wv = w4[t4];
    const float4 bv = b4[t4];
    #pragma unroll 1
    for (; i < n4; i += stride) {
        const int row = (int)(i >> 10);
        out4[i] = fma4(q0[row], wv, bv);
    }
}

// General column-stationary fallback (round-4 kernel, 96.4 us).
__global__ __launch_bounds__(256)
void pn_colkernel(const float* __restrict__ q0,
                  const float4* __restrict__ w4,
                  const float4* __restrict__ b4,
                  float4* __restrict__ out4,
                  int T4, int rows_per_blk) {
    const int t4 = blockIdx.y * blockDim.x + threadIdx.x;
    const float4 wv = w4[t4];
    const float4 bv = b4[t4];
    const int r0 = blockIdx.x * rows_per_blk;

    #pragma unroll 1
    for (int r = 0; r < rows_per_blk; r += 4) {
        const float4 qv = *reinterpret_cast<const float4*>(q0 + r0 + r);
        const long long base = (long long)(r0 + r) * T4 + t4;
        out4[base]           = fma4(qv.x, wv, bv);
        out4[base + T4]      = fma4(qv.y, wv, bv);
        out4[base + 2 * T4]  = fma4(qv.z, wv, bv);
        out4[base + 3 * T4]  = fma4(qv.w, wv, bv);
    }
}

// Scalar fallback for odd shapes.
__global__ __launch_bounds__(256)
void pn_rowkernel_scalar(const float* __restrict__ q0,
                         const float* __restrict__ w,
                         const float* __restrict__ b,
                         float* __restrict__ out,
                         int T) {
    const int row = blockIdx.x;
    const float q = q0[row];
    float* __restrict__ orow = out + (long long)row * T;
    for (int j = threadIdx.x; j < T; j += blockDim.x) {
        orow[j] = fmaf(q, w[j], b[j]);
    }
}

extern "C" void kernel_launch(void* const* d_in, const int* in_sizes, int n_in,
                              void* d_out, int out_size, void* d_ws, size_t ws_size,
                              hipStream_t stream) {
    const float* q0 = (const float*)d_in[0];   // [B, 1]
    const float* w  = (const float*)d_in[1];   // [T]
    const float* b  = (const float*)d_in[2];   // [T]
    float* out = (float*)d_out;                // [B, T, 1]

    const int B = in_sizes[0];
    const int T = in_sizes[1];

    if (T == 4096) {
        const long long n4 = (long long)B * 1024;   // float4 count
        pn_gridstride<<<2048, 256, 0, stream>>>(
            q0,
            reinterpret_cast<const float4*>(w),
            reinterpret_cast<const float4*>(b),
            reinterpret_cast<float4*>(out),
            n4);
        return;
    }

    if ((T & 3) == 0) {
        const int T4 = T >> 2;
        const int rows_per_blk = 64;
        if ((T4 % 256) == 0 && (B % rows_per_blk) == 0) {
            dim3 grid(B / rows_per_blk, T4 / 256);
            pn_colkernel<<<grid, 256, 0, stream>>>(
                q0,
                reinterpret_cast<const float4*>(w),
                reinterpret_cast<const float4*>(b),
                reinterpret_cast<float4*>(out),
                T4, rows_per_blk);
            return;
        }
    }
    pn_rowkernel_scalar<<<B, 256, 0, stream>>>(q0, w, b, out, T);
}

// Round 7
// 96.434 us; speedup vs baseline: 1.8108x; 1.1128x over previous
//
#include <hip/hip_runtime.h>
#include <hip/hip_bf16.h>

// out[b, t] = w[t] * q0[b] + b[t]   (B x T x 1 output, fp32)
// Best-measured config (R4, 96.4 us = 5.57 TB/s write):
// Column-stationary: each block owns a 256-float4 chunk of t, w/b live in
// registers (zero refetch), block sweeps 64 rows, 4 rows per iteration.
// Plain float4 stores (NT hint measured 1.4% slower, R2 A/B).

__device__ inline float4 fma4(float q, const float4& w, const float4& b) {
    float4 o;
    o.x = fmaf(q, w.x, b.x);
    o.y = fmaf(q, w.y, b.y);
    o.z = fmaf(q, w.z, b.z);
    o.w = fmaf(q, w.w, b.w);
    return o;
}

__global__ __launch_bounds__(256)
void pn_colkernel(const float* __restrict__ q0,
                  const float4* __restrict__ w4,
                  const float4* __restrict__ b4,
                  float4* __restrict__ out4,
                  int T4, int rows_per_blk) {
    const int t4 = blockIdx.y * blockDim.x + threadIdx.x;
    const float4 wv = w4[t4];
    const float4 bv = b4[t4];
    const int r0 = blockIdx.x * rows_per_blk;

    #pragma unroll 1
    for (int r = 0; r < rows_per_blk; r += 4) {
        const float4 qv = *reinterpret_cast<const float4*>(q0 + r0 + r);
        const long long base = (long long)(r0 + r) * T4 + t4;
        out4[base]           = fma4(qv.x, wv, bv);
        out4[base + T4]      = fma4(qv.y, wv, bv);
        out4[base + 2 * T4]  = fma4(qv.z, wv, bv);
        out4[base + 3 * T4]  = fma4(qv.w, wv, bv);
    }
}

// Scalar fallback for odd shapes.
__global__ __launch_bounds__(256)
void pn_rowkernel_scalar(const float* __restrict__ q0,
                         const float* __restrict__ w,
                         const float* __restrict__ b,
                         float* __restrict__ out,
                         int T) {
    const int row = blockIdx.x;
    const float q = q0[row];
    float* __restrict__ orow = out + (long long)row * T;
    for (int j = threadIdx.x; j < T; j += blockDim.x) {
        orow[j] = fmaf(q, w[j], b[j]);
    }
}

extern "C" void kernel_launch(void* const* d_in, const int* in_sizes, int n_in,
                              void* d_out, int out_size, void* d_ws, size_t ws_size,
                              hipStream_t stream) {
    const float* q0 = (const float*)d_in[0];   // [B, 1]
    const float* w  = (const float*)d_in[1];   // [T]
    const float* b  = (const float*)d_in[2];   // [T]
    float* out = (float*)d_out;                // [B, T, 1]

    const int B = in_sizes[0];
    const int T = in_sizes[1];

    if ((T & 3) == 0) {
        const int T4 = T >> 2;
        const int rows_per_blk = 64;
        if ((T4 % 256) == 0 && (B % rows_per_blk) == 0) {
            dim3 grid(B / rows_per_blk, T4 / 256);   // (512, 4) at B=32768,T=4096
            pn_colkernel<<<grid, 256, 0, stream>>>(
                q0,
                reinterpret_cast<const float4*>(w),
                reinterpret_cast<const float4*>(b),
                reinterpret_cast<float4*>(out),
                T4, rows_per_blk);
            return;
        }
    }
    pn_rowkernel_scalar<<<B, 256, 0, stream>>>(q0, w, b, out, T);
}